// Round 4
// baseline (40.075 us; speedup 1.0000x reference)
//
#include <hip/hip_runtime.h>
#include <math.h>

#define B_ 8
#define C_ 512
#define T_ 64
#define W_ 14
#define H_ 14
#define N_ 3
#define EPSF 1e-6f
#define WH (W_*H_)          /* 196 */
#define TWH (T_*W_*H_)      /* 12544 */
#define NF4 (TWH/4)         /* 3136 = 12*256 + 64 */

// Single fused kernel: one block per (b,c).
// Phase 1: waves 0..2 compute Gaussian n's separable weights (butterfly sums).
// Phase 2: fully-unrolled float4 stream of the block's 50 KB chunk — all 12
//   loads issued up front for deep MLP, then the weighted accumulation.
__global__ __launch_bounds__(256) void TSF_fused_kernel(
        const float* __restrict__ video,
        const float* __restrict__ length,
        const float* __restrict__ mu_t,
        const float* __restrict__ mu_x,
        const float* __restrict__ mu_y,
        const float* __restrict__ sigma_t,
        const float* __restrict__ sigma_x,
        const float* __restrict__ sigma_y,
        float* __restrict__ out)
{
    const int bc  = blockIdx.x;       // b*C + c
    const int b   = bc >> 9;          // C_ = 512
    const int tid = threadIdx.x;
    const int wave = tid >> 6;
    const int lane = tid & 63;

    __shared__ float s_wt[N_][T_];
    __shared__ float s_wxy[N_][WH];   // rows are 784 B = 49*16 B -> 16B aligned

    if (wave < N_) {
        const int n = wave;
        float st = expf(1.5f - 2.0f*fabsf(tanhf(sigma_t[n])));
        float sx = expf(1.5f - 2.0f*fabsf(tanhf(sigma_x[n])));
        float sy = expf(1.5f - 2.0f*fabsf(tanhf(sigma_y[n])));
        float pt = 1.0f/(st*st + EPSF);
        float px = 1.0f/(sx*sx + EPSF);
        float py = 1.0f/(sy*sy + EPSF);
        float mt = (length[b] - 1.0f) * (tanhf(mu_t[n]) + 1.0f) * 0.5f;
        float mx = (float)(W_-1) * (tanhf(mu_x[n]) + 1.0f) * 0.5f;
        float my = (float)(H_-1) * (tanhf(mu_y[n]) + 1.0f) * 0.5f;

        // temporal: lane == t
        float dtv = (float)lane - mt;
        float ftv = expf(-0.5f*pt*dtv*dtv);
        float sft = ftv;
        #pragma unroll
        for (int off = 1; off < 64; off <<= 1)
            sft += __shfl_xor(sft, off, 64);

        // spatial: r = lane, lane+64, lane+128, lane+192(<196)
        float swxy = 0.f;
        #pragma unroll
        for (int k = 0; k < 4; ++k) {
            int r = lane + 64*k;
            if (r < WH) {
                int w = r / H_;
                int h = r - w*H_;
                float dx = (float)w - mx;
                float dy = (float)h - my;
                float v = expf(-0.5f*(px*dx*dx + py*dy*dy));
                s_wxy[n][r] = v;
                swxy += v;
            }
        }
        #pragma unroll
        for (int off = 1; off < 64; off <<= 1)
            swxy += __shfl_xor(swxy, off, 64);

        float norm = 1.0f / (sft*swxy + EPSF);
        s_wt[n][lane] = ftv * norm;
    }
    __syncthreads();

    // Phase 2: stream video, fully unrolled (static trip count).
    const float4* vp = (const float4*)(video + (size_t)bc * TWH);
    float a0 = 0.f, a1 = 0.f, a2 = 0.f;

#define ACCUM(vv, pp) do {                                            \
        int t_ = (int)((unsigned)(pp) / 49u);                         \
        int r_ = ((pp) - t_*49) << 2;                                 \
        float4 w0 = *(const float4*)&s_wxy[0][r_];                    \
        float4 w1 = *(const float4*)&s_wxy[1][r_];                    \
        float4 w2 = *(const float4*)&s_wxy[2][r_];                    \
        a0 += s_wt[0][t_]*(vv.x*w0.x + vv.y*w0.y + vv.z*w0.z + vv.w*w0.w); \
        a1 += s_wt[1][t_]*(vv.x*w1.x + vv.y*w1.y + vv.z*w1.z + vv.w*w1.w); \
        a2 += s_wt[2][t_]*(vv.x*w2.x + vv.y*w2.y + vv.z*w2.z + vv.w*w2.w); \
    } while (0)

    // Issue all 12 loads back-to-back (independent addresses -> deep MLP).
    float4 v0  = vp[tid + 256*0];
    float4 v1  = vp[tid + 256*1];
    float4 v2  = vp[tid + 256*2];
    float4 v3  = vp[tid + 256*3];
    float4 v4  = vp[tid + 256*4];
    float4 v5  = vp[tid + 256*5];
    float4 v6  = vp[tid + 256*6];
    float4 v7  = vp[tid + 256*7];
    float4 v8  = vp[tid + 256*8];
    float4 v9  = vp[tid + 256*9];
    float4 v10 = vp[tid + 256*10];
    float4 v11 = vp[tid + 256*11];

    ACCUM(v0,  tid + 256*0);
    ACCUM(v1,  tid + 256*1);
    ACCUM(v2,  tid + 256*2);
    ACCUM(v3,  tid + 256*3);
    ACCUM(v4,  tid + 256*4);
    ACCUM(v5,  tid + 256*5);
    ACCUM(v6,  tid + 256*6);
    ACCUM(v7,  tid + 256*7);
    ACCUM(v8,  tid + 256*8);
    ACCUM(v9,  tid + 256*9);
    ACCUM(v10, tid + 256*10);
    ACCUM(v11, tid + 256*11);

    if (tid < 64) {                    // tail: 3136 - 12*256 = 64 float4s
        float4 vt = vp[tid + 256*12];
        ACCUM(vt, tid + 256*12);
    }
#undef ACCUM

    // wave(64) shuffle reduce
    #pragma unroll
    for (int off = 32; off > 0; off >>= 1) {
        a0 += __shfl_down(a0, off, 64);
        a1 += __shfl_down(a1, off, 64);
        a2 += __shfl_down(a2, off, 64);
    }
    __shared__ float s_red[4][N_];
    if (lane == 0) {
        s_red[wave][0] = a0; s_red[wave][1] = a1; s_red[wave][2] = a2;
    }
    __syncthreads();
    if (tid < N_) {
        float s = s_red[0][tid] + s_red[1][tid] + s_red[2][tid] + s_red[3][tid];
        out[(size_t)bc * N_ + tid] = s;   // out[b][c*N + n]
    }
}

extern "C" void kernel_launch(void* const* d_in, const int* in_sizes, int n_in,
                              void* d_out, int out_size, void* d_ws, size_t ws_size,
                              hipStream_t stream) {
    const float* video   = (const float*)d_in[0];
    const float* length  = (const float*)d_in[1];
    const float* mu_t    = (const float*)d_in[2];
    const float* mu_x    = (const float*)d_in[3];
    const float* mu_y    = (const float*)d_in[4];
    const float* sigma_t = (const float*)d_in[5];
    const float* sigma_x = (const float*)d_in[6];
    const float* sigma_y = (const float*)d_in[7];

    TSF_fused_kernel<<<B_*C_, 256, 0, stream>>>(video, length, mu_t, mu_x, mu_y,
                                                sigma_t, sigma_x, sigma_y,
                                                (float*)d_out);
}

// Round 5
// 38.543 us; speedup vs baseline: 1.0398x; 1.0398x over previous
//
#include <hip/hip_runtime.h>
#include <math.h>

#define B_ 8
#define C_ 512
#define T_ 64
#define W_ 14
#define H_ 14
#define N_ 3
#define EPSF 1e-6f
#define WH (W_*H_)          /* 196 */
#define TWH (T_*W_*H_)      /* 12544 */
#define NF4 (TWH/4)         /* 3136 */
#define SWZ(k) ((k) + (((k) >> 5) << 3))   /* bank-spread: +8 floats per 32-group */

// Single fused kernel: one block per (b,c).
// Phase 1: waves 0..2 compute Gaussian n's separable weights (butterfly sums).
//          s_wxy stored SWIZZLED: element k at k+8*(k>>5) -> <=2-way bank alias.
// Phase 2: grid-stride float4 stream (low VGPR -> 8 waves/SIMD TLP).
__global__ __launch_bounds__(256) void TSF_fused_kernel(
        const float* __restrict__ video,
        const float* __restrict__ length,
        const float* __restrict__ mu_t,
        const float* __restrict__ mu_x,
        const float* __restrict__ mu_y,
        const float* __restrict__ sigma_t,
        const float* __restrict__ sigma_x,
        const float* __restrict__ sigma_y,
        float* __restrict__ out)
{
    const int bc  = blockIdx.x;       // b*C + c
    const int b   = bc >> 9;          // C_ = 512
    const int tid = threadIdx.x;
    const int wave = tid >> 6;
    const int lane = tid & 63;

    __shared__ float s_wt[N_][T_];
    __shared__ float s_wxy[N_][256];  // swizzled rows: max index 195+48=243

    if (wave < N_) {
        const int n = wave;
        float st = expf(1.5f - 2.0f*fabsf(tanhf(sigma_t[n])));
        float sx = expf(1.5f - 2.0f*fabsf(tanhf(sigma_x[n])));
        float sy = expf(1.5f - 2.0f*fabsf(tanhf(sigma_y[n])));
        float pt = 1.0f/(st*st + EPSF);
        float px = 1.0f/(sx*sx + EPSF);
        float py = 1.0f/(sy*sy + EPSF);
        float mt = (length[b] - 1.0f) * (tanhf(mu_t[n]) + 1.0f) * 0.5f;
        float mx = (float)(W_-1) * (tanhf(mu_x[n]) + 1.0f) * 0.5f;
        float my = (float)(H_-1) * (tanhf(mu_y[n]) + 1.0f) * 0.5f;

        // temporal: lane == t
        float dtv = (float)lane - mt;
        float ftv = expf(-0.5f*pt*dtv*dtv);
        float sft = ftv;
        #pragma unroll
        for (int off = 1; off < 64; off <<= 1)
            sft += __shfl_xor(sft, off, 64);

        // spatial: r = lane, lane+64, lane+128, lane+192(<196)
        float swxy = 0.f;
        #pragma unroll
        for (int k = 0; k < 4; ++k) {
            int r = lane + 64*k;
            if (r < WH) {
                int w = r / H_;
                int h = r - w*H_;
                float dx = (float)w - mx;
                float dy = (float)h - my;
                float v = expf(-0.5f*(px*dx*dx + py*dy*dy));
                s_wxy[n][SWZ(r)] = v;
                swxy += v;
            }
        }
        #pragma unroll
        for (int off = 1; off < 64; off <<= 1)
            swxy += __shfl_xor(swxy, off, 64);

        float norm = 1.0f / (sft*swxy + EPSF);
        s_wt[n][lane] = ftv * norm;
    }
    __syncthreads();

    // Phase 2: stream video
    const float4* vp = (const float4*)(video + (size_t)bc * TWH);
    float a0 = 0.f, a1 = 0.f, a2 = 0.f;
    for (int p = tid; p < NF4; p += 256) {
        float4 v = vp[p];
        int e = p << 2;
        int t = e / WH;               // magic-mul div by 196
        int r = e - t*WH;             // r % 4 == 0 -> all 4 elems in one 32-group
        int s = SWZ(r);
        float4 w0 = *(const float4*)&s_wxy[0][s];
        float4 w1 = *(const float4*)&s_wxy[1][s];
        float4 w2 = *(const float4*)&s_wxy[2][s];
        float d0 = v.x*w0.x + v.y*w0.y + v.z*w0.z + v.w*w0.w;
        float d1 = v.x*w1.x + v.y*w1.y + v.z*w1.z + v.w*w1.w;
        float d2 = v.x*w2.x + v.y*w2.y + v.z*w2.z + v.w*w2.w;
        a0 += s_wt[0][t]*d0;
        a1 += s_wt[1][t]*d1;
        a2 += s_wt[2][t]*d2;
    }

    // wave(64) shuffle reduce
    #pragma unroll
    for (int off = 32; off > 0; off >>= 1) {
        a0 += __shfl_down(a0, off, 64);
        a1 += __shfl_down(a1, off, 64);
        a2 += __shfl_down(a2, off, 64);
    }
    __shared__ float s_red[4][N_];
    if (lane == 0) {
        s_red[wave][0] = a0; s_red[wave][1] = a1; s_red[wave][2] = a2;
    }
    __syncthreads();
    if (tid < N_) {
        float s = s_red[0][tid] + s_red[1][tid] + s_red[2][tid] + s_red[3][tid];
        out[(size_t)bc * N_ + tid] = s;   // out[b][c*N + n]
    }
}

extern "C" void kernel_launch(void* const* d_in, const int* in_sizes, int n_in,
                              void* d_out, int out_size, void* d_ws, size_t ws_size,
                              hipStream_t stream) {
    const float* video   = (const float*)d_in[0];
    const float* length  = (const float*)d_in[1];
    const float* mu_t    = (const float*)d_in[2];
    const float* mu_x    = (const float*)d_in[3];
    const float* mu_y    = (const float*)d_in[4];
    const float* sigma_t = (const float*)d_in[5];
    const float* sigma_x = (const float*)d_in[6];
    const float* sigma_y = (const float*)d_in[7];

    TSF_fused_kernel<<<B_*C_, 256, 0, stream>>>(video, length, mu_t, mu_x, mu_y,
                                                sigma_t, sigma_x, sigma_y,
                                                (float*)d_out);
}

// Round 6
// 37.818 us; speedup vs baseline: 1.0597x; 1.0192x over previous
//
#include <hip/hip_runtime.h>
#include <math.h>

#define B_ 8
#define C_ 512
#define T_ 64
#define W_ 14
#define H_ 14
#define N_ 3
#define EPSF 1e-6f
#define WH (W_*H_)          /* 196 */
#define TWH (T_*W_*H_)      /* 12544 */
#define NF4 (TWH/4)         /* 3136 = 12*256 + 64 */
#define NBLK (B_*C_/2)      /* 2048 persistent blocks, 2 chunks each */
#define SWZ(k) ((k) + (((k) >> 5) << 3))   /* bank-spread swizzle */

// 2048 blocks; block handles chunks bc0=blk and bc1=blk+2048 (b1 = b0+4).
// Phase 1: waves 0..2 compute Gaussian n's weights; wxy shared across chunks,
//          wt per-chunk (depends on b via length[b]).
// Phase 2: single loop streams BOTH chunks at the same p -> shared address
//          math + shared wxy LDS reads, 2 KB HBM in flight per wave-iter.
__global__ __launch_bounds__(256) void TSF_fused_kernel(
        const float* __restrict__ video,
        const float* __restrict__ length,
        const float* __restrict__ mu_t,
        const float* __restrict__ mu_x,
        const float* __restrict__ mu_y,
        const float* __restrict__ sigma_t,
        const float* __restrict__ sigma_x,
        const float* __restrict__ sigma_y,
        float* __restrict__ out)
{
    const int blk  = blockIdx.x;
    const int b0   = blk >> 9;        // C_=512; b0 in 0..3
    const int tid  = threadIdx.x;
    const int wave = tid >> 6;
    const int lane = tid & 63;

    __shared__ float s_wt[2][N_][T_];
    __shared__ float s_wxy[N_][256];  // swizzled rows

    if (wave < N_) {
        const int n = wave;
        float st = expf(1.5f - 2.0f*fabsf(tanhf(sigma_t[n])));
        float sx = expf(1.5f - 2.0f*fabsf(tanhf(sigma_x[n])));
        float sy = expf(1.5f - 2.0f*fabsf(tanhf(sigma_y[n])));
        float pt = 1.0f/(st*st + EPSF);
        float px = 1.0f/(sx*sx + EPSF);
        float py = 1.0f/(sy*sy + EPSF);
        float tm = (tanhf(mu_t[n]) + 1.0f) * 0.5f;
        float mt0 = (length[b0]     - 1.0f) * tm;
        float mt1 = (length[b0 + 4] - 1.0f) * tm;
        float mx = (float)(W_-1) * (tanhf(mu_x[n]) + 1.0f) * 0.5f;
        float my = (float)(H_-1) * (tanhf(mu_y[n]) + 1.0f) * 0.5f;

        // temporal: lane == t, both chunks (independent chains -> ILP)
        float d0 = (float)lane - mt0;
        float d1 = (float)lane - mt1;
        float ft0 = expf(-0.5f*pt*d0*d0);
        float ft1 = expf(-0.5f*pt*d1*d1);
        float sf0 = ft0, sf1 = ft1;
        #pragma unroll
        for (int off = 1; off < 64; off <<= 1) {
            sf0 += __shfl_xor(sf0, off, 64);
            sf1 += __shfl_xor(sf1, off, 64);
        }

        // spatial: r = lane, lane+64, lane+128, lane+192(<196)
        float swxy = 0.f;
        #pragma unroll
        for (int k = 0; k < 4; ++k) {
            int r = lane + 64*k;
            if (r < WH) {
                int w = r / H_;
                int h = r - w*H_;
                float dx = (float)w - mx;
                float dy = (float)h - my;
                float v = expf(-0.5f*(px*dx*dx + py*dy*dy));
                s_wxy[n][SWZ(r)] = v;
                swxy += v;
            }
        }
        #pragma unroll
        for (int off = 1; off < 64; off <<= 1)
            swxy += __shfl_xor(swxy, off, 64);

        s_wt[0][n][lane] = ft0 * (1.0f/(sf0*swxy + EPSF));
        s_wt[1][n][lane] = ft1 * (1.0f/(sf1*swxy + EPSF));
    }
    __syncthreads();

    // Phase 2: stream both chunks together.
    const float4* vp0 = (const float4*)(video + (size_t)blk * TWH);
    const float4* vp1 = vp0 + (size_t)NBLK * NF4;
    float a0 = 0.f, a1 = 0.f, a2 = 0.f;     // chunk 0
    float c0 = 0.f, c1 = 0.f, c2 = 0.f;     // chunk 1
    for (int p = tid; p < NF4; p += 256) {
        float4 va = vp0[p];
        float4 vb = vp1[p];
        int e = p << 2;
        int t = e / WH;               // magic-mul div
        int r = e - t*WH;             // r % 4 == 0
        int s = SWZ(r);
        float4 w0 = *(const float4*)&s_wxy[0][s];
        float4 w1 = *(const float4*)&s_wxy[1][s];
        float4 w2 = *(const float4*)&s_wxy[2][s];
        float da0 = va.x*w0.x + va.y*w0.y + va.z*w0.z + va.w*w0.w;
        float da1 = va.x*w1.x + va.y*w1.y + va.z*w1.z + va.w*w1.w;
        float da2 = va.x*w2.x + va.y*w2.y + va.z*w2.z + va.w*w2.w;
        float db0 = vb.x*w0.x + vb.y*w0.y + vb.z*w0.z + vb.w*w0.w;
        float db1 = vb.x*w1.x + vb.y*w1.y + vb.z*w1.z + vb.w*w1.w;
        float db2 = vb.x*w2.x + vb.y*w2.y + vb.z*w2.z + vb.w*w2.w;
        a0 += s_wt[0][0][t]*da0;
        a1 += s_wt[0][1][t]*da1;
        a2 += s_wt[0][2][t]*da2;
        c0 += s_wt[1][0][t]*db0;
        c1 += s_wt[1][1][t]*db1;
        c2 += s_wt[1][2][t]*db2;
    }

    // wave(64) shuffle reduce, both chunks
    #pragma unroll
    for (int off = 32; off > 0; off >>= 1) {
        a0 += __shfl_down(a0, off, 64);
        a1 += __shfl_down(a1, off, 64);
        a2 += __shfl_down(a2, off, 64);
        c0 += __shfl_down(c0, off, 64);
        c1 += __shfl_down(c1, off, 64);
        c2 += __shfl_down(c2, off, 64);
    }
    __shared__ float s_red[2][4][N_];
    if (lane == 0) {
        s_red[0][wave][0] = a0; s_red[0][wave][1] = a1; s_red[0][wave][2] = a2;
        s_red[1][wave][0] = c0; s_red[1][wave][1] = c1; s_red[1][wave][2] = c2;
    }
    __syncthreads();
    if (tid < 2*N_) {
        int chunk = tid / N_;
        int n     = tid - chunk*N_;
        float s = s_red[chunk][0][n] + s_red[chunk][1][n]
                + s_red[chunk][2][n] + s_red[chunk][3][n];
        size_t bc = (size_t)blk + (size_t)chunk * NBLK;
        out[bc * N_ + n] = s;
    }
}

extern "C" void kernel_launch(void* const* d_in, const int* in_sizes, int n_in,
                              void* d_out, int out_size, void* d_ws, size_t ws_size,
                              hipStream_t stream) {
    const float* video   = (const float*)d_in[0];
    const float* length  = (const float*)d_in[1];
    const float* mu_t    = (const float*)d_in[2];
    const float* mu_x    = (const float*)d_in[3];
    const float* mu_y    = (const float*)d_in[4];
    const float* sigma_t = (const float*)d_in[5];
    const float* sigma_x = (const float*)d_in[6];
    const float* sigma_y = (const float*)d_in[7];

    TSF_fused_kernel<<<NBLK, 256, 0, stream>>>(video, length, mu_t, mu_x, mu_y,
                                               sigma_t, sigma_x, sigma_y,
                                               (float*)d_out);
}